// Round 1
// baseline (523.752 us; speedup 1.0000x reference)
//
#include <hip/hip_runtime.h>
#include <cstdint>
#include <cstddef>

// Problem constants (fixed by reference)
constexpr int Bc = 8, Tc = 2048, Dc = 1024, Sc = 128, Hc = 256, Ec = 8;
constexpr int NTOK = Bc * Tc;          // 16384 tokens
constexpr int K4S  = 4 * Sc;           // 512

// ---------------------------------------------------------------------------
// Routing: murmur hash -> expert; counting sort of token indices by expert.
// ---------------------------------------------------------------------------
__global__ void k_zero(int* __restrict__ counts) {
  if (threadIdx.x < Ec) counts[threadIdx.x] = 0;
}

__global__ void k_route(const int* __restrict__ tok_ids,
                        int* __restrict__ routes,
                        int* __restrict__ counts) {
  __shared__ int lh[Ec];
  const int tid = threadIdx.x;
  if (tid < Ec) lh[tid] = 0;
  __syncthreads();
  const int i = blockIdx.x * blockDim.x + tid;
  uint32_t v = (uint32_t)tok_ids[i];
  v ^= v >> 16; v *= 2246822507u;
  v ^= v >> 13; v *= 3266489909u;
  v ^= v >> 16;
  const int r = (int)(v % (uint32_t)Ec);
  routes[i] = r;
  atomicAdd(&lh[r], 1);
  __syncthreads();
  if (tid < Ec) atomicAdd(&counts[tid], lh[tid]);
}

__global__ void k_offsets(const int* __restrict__ counts,
                          int* __restrict__ offs,
                          int* __restrict__ cursors) {
  if (threadIdx.x == 0) {
    int s = 0;
    for (int e = 0; e < Ec; e++) { offs[e] = s; cursors[e] = s; s += counts[e]; }
  }
}

__global__ void k_scatter(const int* __restrict__ routes,
                          int* __restrict__ cursors,
                          int* __restrict__ tok_list) {
  __shared__ int lh[Ec], lb[Ec];
  const int tid = threadIdx.x;
  if (tid < Ec) lh[tid] = 0;
  __syncthreads();
  const int i = blockIdx.x * blockDim.x + tid;
  const int r = routes[i];
  const int my = atomicAdd(&lh[r], 1);
  __syncthreads();
  if (tid < Ec) lb[tid] = atomicAdd(&cursors[tid], lh[tid]);
  __syncthreads();
  tok_list[lb[r] + my] = i;
}

// ---------------------------------------------------------------------------
// Tiled fp32 GEMM template structure (hand-instantiated 3x):
//  64 tokens x 128 cols per block, KC=32 staged in LDS.
//  Xs is K-major transposed [32][68] (pad 68 keeps float4 16B-aligned,
//  reads are <=2-way bank aliased = free). Ws is [32][128].
//  256 threads: tx = tid&15 (cols tx*8..+7), ty = tid>>4 (rows ty*4..+3).
// ---------------------------------------------------------------------------

// GEMM1: [u | selh] = gather(x) @ [W_in | W_sel_in];  z=0 -> u, z=1,2 -> selh
__global__ __launch_bounds__(256) void k_gemm1(
    const float* __restrict__ x, const float* __restrict__ W_in,
    const float* __restrict__ W_sel_in,
    const int* __restrict__ tok_list, const int* __restrict__ offs,
    const int* __restrict__ counts,
    float* __restrict__ u, float* __restrict__ selh) {
  const int e = blockIdx.y;
  const int cnt = counts[e];
  const int row0 = (int)blockIdx.x * 64;
  if (row0 >= cnt) return;
  const int z = blockIdx.z;

  __shared__ int toks[64];
  __shared__ float Xs[32][68];
  __shared__ float Ws[32][128];

  const int tid = threadIdx.x;
  if (tid < 64) toks[tid] = tok_list[offs[e] + min(row0 + tid, cnt - 1)];
  __syncthreads();

  const int tx = tid & 15, ty = tid >> 4;
  float acc[4][8];
#pragma unroll
  for (int i = 0; i < 4; i++)
#pragma unroll
    for (int j = 0; j < 8; j++) acc[i][j] = 0.f;

  const float* Wb;
  int wstr, c0;
  if (z == 0) { Wb = W_in + (size_t)e * Dc * Sc; wstr = Sc; c0 = 0; }
  else        { Wb = W_sel_in + (size_t)e * Dc * Hc; wstr = Hc; c0 = (z - 1) * 128; }

  for (int k0 = 0; k0 < Dc; k0 += 32) {
#pragma unroll
    for (int l = 0; l < 2; l++) {
      const int idx = tid + l * 256;
      const int row = idx >> 3, seg = idx & 7;
      const float4 v = *(const float4*)(x + (size_t)toks[row] * Dc + k0 + seg * 4);
      Xs[seg * 4 + 0][row] = v.x; Xs[seg * 4 + 1][row] = v.y;
      Xs[seg * 4 + 2][row] = v.z; Xs[seg * 4 + 3][row] = v.w;
    }
#pragma unroll
    for (int l = 0; l < 4; l++) {
      const int idx = tid + l * 256;
      const int row = idx >> 5, cs = idx & 31;
      *(float4*)(&Ws[row][cs * 4]) =
          *(const float4*)(Wb + (size_t)(k0 + row) * wstr + c0 + cs * 4);
    }
    __syncthreads();
#pragma unroll
    for (int kk = 0; kk < 32; kk++) {
      float a4[4], b8[8];
      *(float4*)a4       = *(const float4*)(&Xs[kk][ty * 4]);
      *(float4*)(b8)     = *(const float4*)(&Ws[kk][tx * 8]);
      *(float4*)(b8 + 4) = *(const float4*)(&Ws[kk][tx * 8 + 4]);
#pragma unroll
      for (int i = 0; i < 4; i++)
#pragma unroll
        for (int j = 0; j < 8; j++) acc[i][j] = fmaf(a4[i], b8[j], acc[i][j]);
    }
    __syncthreads();
  }

#pragma unroll
  for (int i = 0; i < 4; i++) {
    const int r = row0 + ty * 4 + i;
    if (r < cnt) {
      const int tok = toks[ty * 4 + i];
      if (z == 0) {
        float4 v0 = make_float4(acc[i][0], acc[i][1], acc[i][2], acc[i][3]);
        float4 v1 = make_float4(acc[i][4], acc[i][5], acc[i][6], acc[i][7]);
        *(float4*)(u + (size_t)tok * Sc + tx * 8)     = v0;
        *(float4*)(u + (size_t)tok * Sc + tx * 8 + 4) = v1;
      } else {
        float o[8];
#pragma unroll
        for (int j = 0; j < 8; j++) {
          const float v = acc[i][j];
          o[j] = v / (1.f + expf(-v));   // silu
        }
        float4 v0 = make_float4(o[0], o[1], o[2], o[3]);
        float4 v1 = make_float4(o[4], o[5], o[6], o[7]);
        *(float4*)(selh + (size_t)tok * Hc + c0 + tx * 8)     = v0;
        *(float4*)(selh + (size_t)tok * Hc + c0 + tx * 8 + 4) = v1;
      }
    }
  }
}

// GEMM2: abcd = gather(selh) @ W_sel_out, fused activations.
// z = 0..3 selects the a/b/c/dg quarter. acts layout per token: [a|bu|c|skip].
__global__ __launch_bounds__(256) void k_gemm2(
    const float* __restrict__ selh, const float* __restrict__ W_sel_out,
    const float* __restrict__ u, const float* __restrict__ d_param,
    const int* __restrict__ tok_list, const int* __restrict__ offs,
    const int* __restrict__ counts,
    float* __restrict__ acts) {
  const int e = blockIdx.y;
  const int cnt = counts[e];
  const int row0 = (int)blockIdx.x * 64;
  if (row0 >= cnt) return;
  const int z = blockIdx.z;

  __shared__ int toks[64];
  __shared__ float Xs[32][68];
  __shared__ float Ws[32][128];

  const int tid = threadIdx.x;
  if (tid < 64) toks[tid] = tok_list[offs[e] + min(row0 + tid, cnt - 1)];
  __syncthreads();

  const int tx = tid & 15, ty = tid >> 4;
  float acc[4][8];
#pragma unroll
  for (int i = 0; i < 4; i++)
#pragma unroll
    for (int j = 0; j < 8; j++) acc[i][j] = 0.f;

  const float* Wb = W_sel_out + (size_t)e * Hc * K4S + z * 128;  // row stride 512

  for (int k0 = 0; k0 < Hc; k0 += 32) {
#pragma unroll
    for (int l = 0; l < 2; l++) {
      const int idx = tid + l * 256;
      const int row = idx >> 3, seg = idx & 7;
      const float4 v = *(const float4*)(selh + (size_t)toks[row] * Hc + k0 + seg * 4);
      Xs[seg * 4 + 0][row] = v.x; Xs[seg * 4 + 1][row] = v.y;
      Xs[seg * 4 + 2][row] = v.z; Xs[seg * 4 + 3][row] = v.w;
    }
#pragma unroll
    for (int l = 0; l < 4; l++) {
      const int idx = tid + l * 256;
      const int row = idx >> 5, cs = idx & 31;
      *(float4*)(&Ws[row][cs * 4]) =
          *(const float4*)(Wb + (size_t)(k0 + row) * K4S + cs * 4);
    }
    __syncthreads();
#pragma unroll
    for (int kk = 0; kk < 32; kk++) {
      float a4[4], b8[8];
      *(float4*)a4       = *(const float4*)(&Xs[kk][ty * 4]);
      *(float4*)(b8)     = *(const float4*)(&Ws[kk][tx * 8]);
      *(float4*)(b8 + 4) = *(const float4*)(&Ws[kk][tx * 8 + 4]);
#pragma unroll
      for (int i = 0; i < 4; i++)
#pragma unroll
        for (int j = 0; j < 8; j++) acc[i][j] = fmaf(a4[i], b8[j], acc[i][j]);
    }
    __syncthreads();
  }

#pragma unroll
  for (int i = 0; i < 4; i++) {
    const int r = row0 + ty * 4 + i;
    if (r < cnt) {
      const int tok = toks[ty * 4 + i];
      const int col = tx * 8;
      float o[8];
      if (z == 0) {                       // a = sigmoid
#pragma unroll
        for (int j = 0; j < 8; j++) o[j] = 1.f / (1.f + expf(-acc[i][j]));
      } else if (z == 1) {                // bu = tanh * u
        const float4 u0 = *(const float4*)(u + (size_t)tok * Sc + col);
        const float4 u1 = *(const float4*)(u + (size_t)tok * Sc + col + 4);
        const float uv[8] = {u0.x, u0.y, u0.z, u0.w, u1.x, u1.y, u1.z, u1.w};
#pragma unroll
        for (int j = 0; j < 8; j++) o[j] = tanhf(acc[i][j]) * uv[j];
      } else if (z == 2) {                // c = tanh
#pragma unroll
        for (int j = 0; j < 8; j++) o[j] = tanhf(acc[i][j]);
      } else {                            // skip = d_param * sigmoid * u
        const float4 u0 = *(const float4*)(u + (size_t)tok * Sc + col);
        const float4 u1 = *(const float4*)(u + (size_t)tok * Sc + col + 4);
        const float uv[8] = {u0.x, u0.y, u0.z, u0.w, u1.x, u1.y, u1.z, u1.w};
        const float4 dp0 = *(const float4*)(d_param + (size_t)e * Sc + col);
        const float4 dp1 = *(const float4*)(d_param + (size_t)e * Sc + col + 4);
        const float dp[8] = {dp0.x, dp0.y, dp0.z, dp0.w, dp1.x, dp1.y, dp1.z, dp1.w};
#pragma unroll
        for (int j = 0; j < 8; j++)
          o[j] = dp[j] * (1.f / (1.f + expf(-acc[i][j]))) * uv[j];
      }
      float4 v0 = make_float4(o[0], o[1], o[2], o[3]);
      float4 v1 = make_float4(o[4], o[5], o[6], o[7]);
      *(float4*)(acts + (size_t)tok * K4S + z * 128 + col)     = v0;
      *(float4*)(acts + (size_t)tok * K4S + z * 128 + col + 4) = v1;
    }
  }
}

// Scan: one block per (b,e); 128 threads = state dim. Build the ordered match
// list in LDS via ballot compaction, then run the h = a*h + bu recurrence.
__global__ __launch_bounds__(128) void k_scan(
    const int* __restrict__ routes, const float* __restrict__ acts,
    float* __restrict__ y) {
  const int b = blockIdx.x;
  const int e = blockIdx.y;
  __shared__ int rts[Tc];
  __shared__ int list[Tc];
  __shared__ int n_sh;
  const int tid = threadIdx.x;
  for (int i = tid; i < Tc; i += 128) rts[i] = routes[b * Tc + i];
  __syncthreads();
  if (tid < 64) {
    int base = 0;
    for (int it = 0; it < Tc / 64; it++) {
      const int t = it * 64 + tid;
      const bool m = (rts[t] == e);
      const unsigned long long mask = __ballot(m);
      const int pre = __popcll(mask & ((1ull << tid) - 1ull));
      if (m) list[base + pre] = t;
      base += __popcll(mask);
    }
    if (tid == 0) n_sh = base;
  }
  __syncthreads();
  const int n = n_sh;
  const int s = tid;
  float h = 0.f;
  for (int i = 0; i < n; i++) {
    const int tok = b * Tc + list[i];
    const float* ap = acts + (size_t)tok * K4S;
    const float a  = ap[s];
    const float bu = ap[128 + s];
    const float c  = ap[256 + s];
    const float sk = ap[384 + s];
    h = fmaf(a, h, bu);
    y[(size_t)tok * Sc + s] = fmaf(c, h, sk);
  }
}

// GEMM3: out = gather(y) @ W_out[e]; z = 0..7 selects 128-col chunk of D=1024.
__global__ __launch_bounds__(256) void k_gemm3(
    const float* __restrict__ y, const float* __restrict__ W_out,
    const int* __restrict__ tok_list, const int* __restrict__ offs,
    const int* __restrict__ counts,
    float* __restrict__ out) {
  const int e = blockIdx.y;
  const int cnt = counts[e];
  const int row0 = (int)blockIdx.x * 64;
  if (row0 >= cnt) return;
  const int z = blockIdx.z;

  __shared__ int toks[64];
  __shared__ float Xs[32][68];
  __shared__ float Ws[32][128];

  const int tid = threadIdx.x;
  if (tid < 64) toks[tid] = tok_list[offs[e] + min(row0 + tid, cnt - 1)];
  __syncthreads();

  const int tx = tid & 15, ty = tid >> 4;
  float acc[4][8];
#pragma unroll
  for (int i = 0; i < 4; i++)
#pragma unroll
    for (int j = 0; j < 8; j++) acc[i][j] = 0.f;

  const float* Wb = W_out + (size_t)e * Sc * Dc + z * 128;  // row stride 1024

  for (int k0 = 0; k0 < Sc; k0 += 32) {
#pragma unroll
    for (int l = 0; l < 2; l++) {
      const int idx = tid + l * 256;
      const int row = idx >> 3, seg = idx & 7;
      const float4 v = *(const float4*)(y + (size_t)toks[row] * Sc + k0 + seg * 4);
      Xs[seg * 4 + 0][row] = v.x; Xs[seg * 4 + 1][row] = v.y;
      Xs[seg * 4 + 2][row] = v.z; Xs[seg * 4 + 3][row] = v.w;
    }
#pragma unroll
    for (int l = 0; l < 4; l++) {
      const int idx = tid + l * 256;
      const int row = idx >> 5, cs = idx & 31;
      *(float4*)(&Ws[row][cs * 4]) =
          *(const float4*)(Wb + (size_t)(k0 + row) * Dc + cs * 4);
    }
    __syncthreads();
#pragma unroll
    for (int kk = 0; kk < 32; kk++) {
      float a4[4], b8[8];
      *(float4*)a4       = *(const float4*)(&Xs[kk][ty * 4]);
      *(float4*)(b8)     = *(const float4*)(&Ws[kk][tx * 8]);
      *(float4*)(b8 + 4) = *(const float4*)(&Ws[kk][tx * 8 + 4]);
#pragma unroll
      for (int i = 0; i < 4; i++)
#pragma unroll
        for (int j = 0; j < 8; j++) acc[i][j] = fmaf(a4[i], b8[j], acc[i][j]);
    }
    __syncthreads();
  }

#pragma unroll
  for (int i = 0; i < 4; i++) {
    const int r = row0 + ty * 4 + i;
    if (r < cnt) {
      const int tok = toks[ty * 4 + i];
      float4 v0 = make_float4(acc[i][0], acc[i][1], acc[i][2], acc[i][3]);
      float4 v1 = make_float4(acc[i][4], acc[i][5], acc[i][6], acc[i][7]);
      *(float4*)(out + (size_t)tok * Dc + z * 128 + tx * 8)     = v0;
      *(float4*)(out + (size_t)tok * Dc + z * 128 + tx * 8 + 4) = v1;
    }
  }
}

// ---------------------------------------------------------------------------
extern "C" void kernel_launch(void* const* d_in, const int* in_sizes, int n_in,
                              void* d_out, int out_size, void* d_ws, size_t ws_size,
                              hipStream_t stream) {
  const float* x         = (const float*)d_in[0];
  const int*   tok_ids   = (const int*)d_in[1];
  const float* W_in      = (const float*)d_in[2];
  const float* W_sel_in  = (const float*)d_in[3];
  const float* W_sel_out = (const float*)d_in[4];
  const float* W_out     = (const float*)d_in[5];
  const float* d_param   = (const float*)d_in[6];
  float* out = (float*)d_out;

  // Workspace carve (all 256B aligned). y aliases u (u dead after k_gemm2).
  char* p = (char*)d_ws;
  auto carve = [&](size_t bytes) -> char* {
    char* r = p;
    p += (bytes + 255) / 256 * 256;
    return r;
  };
  int* routes   = (int*)carve((size_t)NTOK * 4);
  int* counts   = (int*)carve(Ec * 4);
  int* offs     = (int*)carve(Ec * 4);
  int* cursors  = (int*)carve(Ec * 4);
  int* tok_list = (int*)carve((size_t)NTOK * 4);
  float* u      = (float*)carve((size_t)NTOK * Sc * 4);
  float* selh   = (float*)carve((size_t)NTOK * Hc * 4);
  float* acts   = (float*)carve((size_t)NTOK * K4S * 4);
  float* yv     = u;  // reuse: u is fully consumed by end of k_gemm2

  k_zero<<<1, 64, 0, stream>>>(counts);
  k_route<<<NTOK / 256, 256, 0, stream>>>(tok_ids, routes, counts);
  k_offsets<<<1, 64, 0, stream>>>(counts, offs, cursors);
  k_scatter<<<NTOK / 256, 256, 0, stream>>>(routes, cursors, tok_list);
  // grid.x = 64 tiles covers up to 4096 tokens/expert (mean 2048, sigma ~48;
  // overflow would fail validation loudly, not silently).
  k_gemm1<<<dim3(64, Ec, 3), 256, 0, stream>>>(x, W_in, W_sel_in, tok_list,
                                               offs, counts, u, selh);
  k_gemm2<<<dim3(64, Ec, 4), 256, 0, stream>>>(selh, W_sel_out, u, d_param,
                                               tok_list, offs, counts, acts);
  k_scan<<<dim3(Bc, Ec), 128, 0, stream>>>(routes, acts, yv);
  k_gemm3<<<dim3(64, Ec, 8), 256, 0, stream>>>(yv, W_out, tok_list, offs,
                                               counts, out);
}

// Round 2
// 387.255 us; speedup vs baseline: 1.3525x; 1.3525x over previous
//
#include <hip/hip_runtime.h>
#include <cstdint>
#include <cstddef>

// Problem constants (fixed by reference)
constexpr int Bc = 8, Tc = 2048, Dc = 1024, Sc = 128, Hc = 256, Ec = 8;
constexpr int NTOK = Bc * Tc;          // 16384 tokens
constexpr int K4S  = 4 * Sc;           // 512

typedef unsigned short u16;
typedef __attribute__((ext_vector_type(8))) short shortx8;   // 8 bf16 = 4 VGPR (MFMA A/B frag)
typedef __attribute__((ext_vector_type(4))) float f32x4;     // MFMA C/D frag

// Split fp32 into bf16 hi (truncated) + bf16 lo (truncated residual).
// v - float(hi) is exact in fp32, so total repr error ~2^-16 relative.
__device__ __forceinline__ void split2(float v, u16& h, u16& l) {
  uint32_t b  = __float_as_uint(v);
  uint32_t hb = b & 0xffff0000u;
  h = (u16)(hb >> 16);
  float lo = v - __uint_as_float(hb);
  l = (u16)(__float_as_uint(lo) >> 16);
}

// Async global->LDS, 16B per lane. dst must be wave-uniform; src is per-lane.
__device__ __forceinline__ void gload16(const void* g, void* l) {
  __builtin_amdgcn_global_load_lds(
      (const __attribute__((address_space(1))) uint32_t*)g,
      (__attribute__((address_space(3))) uint32_t*)l, 16, 0, 0);
}

__device__ __forceinline__ float sigf(float v) { return 1.f / (1.f + expf(-v)); }

// ---------------------------------------------------------------------------
// Routing: murmur hash -> expert; counting sort of token indices by expert.
// ---------------------------------------------------------------------------
__global__ void k_zero(int* __restrict__ counts) {
  if (threadIdx.x < Ec) counts[threadIdx.x] = 0;
}

__global__ void k_route(const int* __restrict__ tok_ids,
                        int* __restrict__ routes,
                        int* __restrict__ counts) {
  __shared__ int lh[Ec];
  const int tid = threadIdx.x;
  if (tid < Ec) lh[tid] = 0;
  __syncthreads();
  const int i = blockIdx.x * blockDim.x + tid;
  uint32_t v = (uint32_t)tok_ids[i];
  v ^= v >> 16; v *= 2246822507u;
  v ^= v >> 13; v *= 3266489909u;
  v ^= v >> 16;
  const int r = (int)(v % (uint32_t)Ec);
  routes[i] = r;
  atomicAdd(&lh[r], 1);
  __syncthreads();
  if (tid < Ec) atomicAdd(&counts[tid], lh[tid]);
}

__global__ void k_offsets(const int* __restrict__ counts,
                          int* __restrict__ offs,
                          int* __restrict__ cursors) {
  if (threadIdx.x == 0) {
    int s = 0;
    for (int e = 0; e < Ec; e++) { offs[e] = s; cursors[e] = s; s += counts[e]; }
  }
}

__global__ void k_scatter(const int* __restrict__ routes,
                          int* __restrict__ cursors,
                          int* __restrict__ tok_list) {
  __shared__ int lh[Ec], lb[Ec];
  const int tid = threadIdx.x;
  if (tid < Ec) lh[tid] = 0;
  __syncthreads();
  const int i = blockIdx.x * blockDim.x + tid;
  const int r = routes[i];
  const int my = atomicAdd(&lh[r], 1);
  __syncthreads();
  if (tid < Ec) lb[tid] = atomicAdd(&cursors[tid], lh[tid]);
  __syncthreads();
  tok_list[lb[r] + my] = i;
}

// ---------------------------------------------------------------------------
// Weight prep: transpose [E][K][N] -> [E][N][K] and split fp32 -> bf16 hi/lo.
// 32x32 tiles via LDS; both global phases coalesced.
// ---------------------------------------------------------------------------
__global__ __launch_bounds__(256) void k_tr_split(
    const float* __restrict__ W_in, const float* __restrict__ W_sel_in,
    const float* __restrict__ W_sel_out, const float* __restrict__ W_out,
    u16* __restrict__ tInH, u16* __restrict__ tInL,
    u16* __restrict__ tSiH, u16* __restrict__ tSiL,
    u16* __restrict__ tSoH, u16* __restrict__ tSoL,
    u16* __restrict__ tOH,  u16* __restrict__ tOL) {
  const int bid = blockIdx.x;
  const float* src; u16* dh; u16* dl; int K, N, local;
  if (bid < 1024)      { src = W_in;      dh = tInH; dl = tInL; K = 1024; N = 128;  local = bid; }
  else if (bid < 3072) { src = W_sel_in;  dh = tSiH; dl = tSiL; K = 1024; N = 256;  local = bid - 1024; }
  else if (bid < 4096) { src = W_sel_out; dh = tSoH; dl = tSoL; K = 256;  N = 512;  local = bid - 3072; }
  else                 { src = W_out;     dh = tOH;  dl = tOL;  K = 128;  N = 1024; local = bid - 4096; }
  const int tn = N / 32, per_e = (K / 32) * tn;
  const int e = local / per_e, r = local % per_e;
  const int k0 = (r / tn) * 32, n0 = (r % tn) * 32;
  src += (size_t)e * K * N;
  dh  += (size_t)e * K * N;
  dl  += (size_t)e * K * N;

  __shared__ float T[32][36];
  const int t = threadIdx.x;
  {
    const int rr = t >> 3, c4 = t & 7;
    const float4 v = *(const float4*)(src + (size_t)(k0 + rr) * N + n0 + c4 * 4);
    T[rr][c4 * 4 + 0] = v.x; T[rr][c4 * 4 + 1] = v.y;
    T[rr][c4 * 4 + 2] = v.z; T[rr][c4 * 4 + 3] = v.w;
  }
  __syncthreads();
  {
    const int nn = t >> 3, kq = t & 7;
    u16 hs[4], ls[4];
#pragma unroll
    for (int j = 0; j < 4; j++) split2(T[kq * 4 + j][nn], hs[j], ls[j]);
    const size_t o = (size_t)(n0 + nn) * K + k0 + kq * 4;
    *(ushort4*)(dh + o) = make_ushort4(hs[0], hs[1], hs[2], hs[3]);
    *(ushort4*)(dl + o) = make_ushort4(ls[0], ls[1], ls[2], ls[3]);
  }
}

// ---------------------------------------------------------------------------
// Split-bf16 MFMA GEMM core (m97 structure): 128x128 tile, BK=32, 4 waves.
// LDS tiles: [128 rows][32 k] bf16, linear (64B rows). Frags via ds_read_b128.
// acc += Ah*Bh + Ah*Bl + Al*Bh (lo*lo dropped).
// A/B frag: lane reads k-chunk (lane>>4)*8 — SAME k mapping for A and B, so
// the HW k-slot permutation cancels. C/D: col=lane&15, row=4*(lane>>4)+reg.
// ---------------------------------------------------------------------------
template<bool CONV>
__device__ __forceinline__ void mm_core(
    const float* Agf,                                   // CONV: per-thread fp32 A src
    const u16* Agh0, const u16* Agh1,                   // !CONV: per-lane A hi src (q=0,1)
    const u16* Agl0, const u16* Agl1,                   //        per-lane A lo src
    const u16* Bgh0, const u16* Bgh1,
    const u16* Bgl0, const u16* Bgl1,
    int K, int tid,
    short* Ah, short* Al, short* Bh, short* Bl,
    f32x4 (&acc)[4][4]) {
  const int w = tid >> 6, l = tid & 63;
  const int lr = l & 15, lg = l >> 4;
  const int wr = (w >> 1) * 64, wc = (w & 1) * 64;
  int aoff[4], boff[4];
#pragma unroll
  for (int i = 0; i < 4; i++) {
    aoff[i] = (wr + i * 16 + lr) * 32 + lg * 8;
    boff[i] = (wc + i * 16 + lr) * 32 + lg * 8;
  }
  // wave-uniform LDS staging destinations (1KB per (wave,q))
  short* AhD0 = Ah + (w * 2 + 0) * 512; short* AhD1 = Ah + (w * 2 + 1) * 512;
  short* AlD0 = Al + (w * 2 + 0) * 512; short* AlD1 = Al + (w * 2 + 1) * 512;
  short* BhD0 = Bh + (w * 2 + 0) * 512; short* BhD1 = Bh + (w * 2 + 1) * 512;
  short* BlD0 = Bl + (w * 2 + 0) * 512; short* BlD1 = Bl + (w * 2 + 1) * 512;
  const int arow = tid >> 1, ahalf = tid & 1;  // CONV staging map

  for (int k0 = 0; k0 < K; k0 += 32) {
    if constexpr (CONV) {
      float4 f[4];
#pragma unroll
      for (int j = 0; j < 4; j++) f[j] = *(const float4*)(Agf + k0 + j * 4);
#pragma unroll
      for (int j = 0; j < 4; j++) {
        u16 h0, l0, h1, l1, h2, l2, h3, l3;
        split2(f[j].x, h0, l0); split2(f[j].y, h1, l1);
        split2(f[j].z, h2, l2); split2(f[j].w, h3, l3);
        const int o = arow * 32 + ahalf * 16 + j * 4;
        *(ushort4*)(Ah + o) = make_ushort4(h0, h1, h2, h3);
        *(ushort4*)(Al + o) = make_ushort4(l0, l1, l2, l3);
      }
    } else {
      gload16(Agh0 + k0, AhD0); gload16(Agh1 + k0, AhD1);
      gload16(Agl0 + k0, AlD0); gload16(Agl1 + k0, AlD1);
    }
    gload16(Bgh0 + k0, BhD0); gload16(Bgh1 + k0, BhD1);
    gload16(Bgl0 + k0, BlD0); gload16(Bgl1 + k0, BlD1);
    __syncthreads();
    shortx8 ah[4], al[4];
#pragma unroll
    for (int mi = 0; mi < 4; mi++) {
      ah[mi] = *(shortx8*)(Ah + aoff[mi]);
      al[mi] = *(shortx8*)(Al + aoff[mi]);
    }
#pragma unroll
    for (int ni = 0; ni < 4; ni++) {
      const shortx8 bh = *(shortx8*)(Bh + boff[ni]);
      const shortx8 bl = *(shortx8*)(Bl + boff[ni]);
#pragma unroll
      for (int mi = 0; mi < 4; mi++) {
        acc[mi][ni] = __builtin_amdgcn_mfma_f32_16x16x32_bf16(ah[mi], bh, acc[mi][ni], 0, 0, 0);
        acc[mi][ni] = __builtin_amdgcn_mfma_f32_16x16x32_bf16(ah[mi], bl, acc[mi][ni], 0, 0, 0);
        acc[mi][ni] = __builtin_amdgcn_mfma_f32_16x16x32_bf16(al[mi], bh, acc[mi][ni], 0, 0, 0);
      }
    }
    __syncthreads();
  }
}

// GEMM1: [u | selh] = gather(x) @ [W_in | W_sel_in]; z=0 -> u, z=1,2 -> selh(silu)
__global__ __launch_bounds__(256) void k_mm1(
    const float* __restrict__ x,
    const u16* __restrict__ tInH, const u16* __restrict__ tInL,
    const u16* __restrict__ tSiH, const u16* __restrict__ tSiL,
    const int* __restrict__ tok_list, const int* __restrict__ offs,
    const int* __restrict__ counts,
    float* __restrict__ u_out, u16* __restrict__ selhH, u16* __restrict__ selhL) {
  const int e = blockIdx.y, z = blockIdx.z;
  const int cnt = counts[e];
  const int row0 = (int)blockIdx.x * 128;
  if (row0 >= cnt) return;
  __shared__ short Ah[4096], Al[4096], Bh[4096], Bl[4096];
  __shared__ int toks[128];
  const int tid = threadIdx.x;
  if (tid < 128) toks[tid] = tok_list[offs[e] + min(row0 + tid, cnt - 1)];
  __syncthreads();
  const int w = tid >> 6, l = tid & 63;
  const u16 *BH, *BL;
  if (z == 0) { BH = tInH + (size_t)e * 128 * 1024; BL = tInL + (size_t)e * 128 * 1024; }
  else { const size_t o = ((size_t)e * 256 + (size_t)(z - 1) * 128) * 1024; BH = tSiH + o; BL = tSiL + o; }
  const int rq0 = w * 32 + (l >> 2), rq1 = rq0 + 16, ch = (l & 3) * 8;
  const u16* Bgh0 = BH + (size_t)rq0 * 1024 + ch; const u16* Bgh1 = BH + (size_t)rq1 * 1024 + ch;
  const u16* Bgl0 = BL + (size_t)rq0 * 1024 + ch; const u16* Bgl1 = BL + (size_t)rq1 * 1024 + ch;
  const float* Agf = x + (size_t)toks[tid >> 1] * Dc + (tid & 1) * 16;

  f32x4 acc[4][4];
#pragma unroll
  for (int i = 0; i < 4; i++)
#pragma unroll
    for (int j = 0; j < 4; j++) acc[i][j] = (f32x4)0.f;

  mm_core<true>(Agf, nullptr, nullptr, nullptr, nullptr,
                Bgh0, Bgh1, Bgl0, Bgl1, 1024, tid, Ah, Al, Bh, Bl, acc);

  const int lr = l & 15, lg = l >> 4;
  const int wr = (w >> 1) * 64, wc = (w & 1) * 64;
#pragma unroll
  for (int mi = 0; mi < 4; mi++)
#pragma unroll
    for (int g = 0; g < 4; g++) {
      const int rl = wr + mi * 16 + lg * 4 + g;
      if (row0 + rl < cnt) {
        const int tok = toks[rl];
#pragma unroll
        for (int ni = 0; ni < 4; ni++) {
          const int cl = wc + ni * 16 + lr;
          const float v = acc[mi][ni][g];
          if (z == 0) {
            u_out[(size_t)tok * Sc + cl] = v;
          } else {
            const float s = v * sigf(v);       // silu
            u16 sh, sl; split2(s, sh, sl);
            const size_t o = (size_t)tok * Hc + (size_t)(z - 1) * 128 + cl;
            selhH[o] = sh; selhL[o] = sl;
          }
        }
      }
    }
}

// GEMM2: abcd = gather(selh) @ W_sel_out, fused activations -> acts [a|bu|c|sk]
__global__ __launch_bounds__(256) void k_mm2(
    const u16* __restrict__ selhH, const u16* __restrict__ selhL,
    const u16* __restrict__ tSoH, const u16* __restrict__ tSoL,
    const float* __restrict__ u_in, const float* __restrict__ d_param,
    const int* __restrict__ tok_list, const int* __restrict__ offs,
    const int* __restrict__ counts,
    float* __restrict__ acts) {
  const int e = blockIdx.y, z = blockIdx.z;
  const int cnt = counts[e];
  const int row0 = (int)blockIdx.x * 128;
  if (row0 >= cnt) return;
  __shared__ short Ah[4096], Al[4096], Bh[4096], Bl[4096];
  __shared__ int toks[128];
  const int tid = threadIdx.x;
  if (tid < 128) toks[tid] = tok_list[offs[e] + min(row0 + tid, cnt - 1)];
  __syncthreads();
  const int w = tid >> 6, l = tid & 63;
  const size_t bo = ((size_t)e * 512 + (size_t)z * 128) * 256;
  const int rq0 = w * 32 + (l >> 2), rq1 = rq0 + 16, ch = (l & 3) * 8;
  const u16* Bgh0 = tSoH + bo + (size_t)rq0 * 256 + ch; const u16* Bgh1 = tSoH + bo + (size_t)rq1 * 256 + ch;
  const u16* Bgl0 = tSoL + bo + (size_t)rq0 * 256 + ch; const u16* Bgl1 = tSoL + bo + (size_t)rq1 * 256 + ch;
  const u16* Agh0 = selhH + (size_t)toks[rq0] * Hc + ch; const u16* Agh1 = selhH + (size_t)toks[rq1] * Hc + ch;
  const u16* Agl0 = selhL + (size_t)toks[rq0] * Hc + ch; const u16* Agl1 = selhL + (size_t)toks[rq1] * Hc + ch;

  f32x4 acc[4][4];
#pragma unroll
  for (int i = 0; i < 4; i++)
#pragma unroll
    for (int j = 0; j < 4; j++) acc[i][j] = (f32x4)0.f;

  mm_core<false>(nullptr, Agh0, Agh1, Agl0, Agl1,
                 Bgh0, Bgh1, Bgl0, Bgl1, 256, tid, Ah, Al, Bh, Bl, acc);

  const int lr = l & 15, lg = l >> 4;
  const int wr = (w >> 1) * 64, wc = (w & 1) * 64;
#pragma unroll
  for (int mi = 0; mi < 4; mi++)
#pragma unroll
    for (int g = 0; g < 4; g++) {
      const int rl = wr + mi * 16 + lg * 4 + g;
      if (row0 + rl < cnt) {
        const int tok = toks[rl];
#pragma unroll
        for (int ni = 0; ni < 4; ni++) {
          const int cl = wc + ni * 16 + lr;
          const float v = acc[mi][ni][g];
          float o;
          if (z == 0)      o = sigf(v);
          else if (z == 1) o = tanhf(v) * u_in[(size_t)tok * Sc + cl];
          else if (z == 2) o = tanhf(v);
          else             o = d_param[e * Sc + cl] * sigf(v) * u_in[(size_t)tok * Sc + cl];
          acts[(size_t)tok * K4S + (size_t)z * 128 + cl] = o;
        }
      }
    }
}

// GEMM3: out = gather(y) @ W_out[e]
__global__ __launch_bounds__(256) void k_mm3(
    const u16* __restrict__ yH, const u16* __restrict__ yL,
    const u16* __restrict__ tOH, const u16* __restrict__ tOL,
    const int* __restrict__ tok_list, const int* __restrict__ offs,
    const int* __restrict__ counts,
    float* __restrict__ out) {
  const int e = blockIdx.y, z = blockIdx.z;
  const int cnt = counts[e];
  const int row0 = (int)blockIdx.x * 128;
  if (row0 >= cnt) return;
  __shared__ short Ah[4096], Al[4096], Bh[4096], Bl[4096];
  __shared__ int toks[128];
  const int tid = threadIdx.x;
  if (tid < 128) toks[tid] = tok_list[offs[e] + min(row0 + tid, cnt - 1)];
  __syncthreads();
  const int w = tid >> 6, l = tid & 63;
  const size_t bo = ((size_t)e * 1024 + (size_t)z * 128) * 128;
  const int rq0 = w * 32 + (l >> 2), rq1 = rq0 + 16, ch = (l & 3) * 8;
  const u16* Bgh0 = tOH + bo + (size_t)rq0 * 128 + ch; const u16* Bgh1 = tOH + bo + (size_t)rq1 * 128 + ch;
  const u16* Bgl0 = tOL + bo + (size_t)rq0 * 128 + ch; const u16* Bgl1 = tOL + bo + (size_t)rq1 * 128 + ch;
  const u16* Agh0 = yH + (size_t)toks[rq0] * Sc + ch; const u16* Agh1 = yH + (size_t)toks[rq1] * Sc + ch;
  const u16* Agl0 = yL + (size_t)toks[rq0] * Sc + ch; const u16* Agl1 = yL + (size_t)toks[rq1] * Sc + ch;

  f32x4 acc[4][4];
#pragma unroll
  for (int i = 0; i < 4; i++)
#pragma unroll
    for (int j = 0; j < 4; j++) acc[i][j] = (f32x4)0.f;

  mm_core<false>(nullptr, Agh0, Agh1, Agl0, Agl1,
                 Bgh0, Bgh1, Bgl0, Bgl1, 128, tid, Ah, Al, Bh, Bl, acc);

  const int lr = l & 15, lg = l >> 4;
  const int wr = (w >> 1) * 64, wc = (w & 1) * 64;
#pragma unroll
  for (int mi = 0; mi < 4; mi++)
#pragma unroll
    for (int g = 0; g < 4; g++) {
      const int rl = wr + mi * 16 + lg * 4 + g;
      if (row0 + rl < cnt) {
        const int tok = toks[rl];
#pragma unroll
        for (int ni = 0; ni < 4; ni++) {
          const int cl = wc + ni * 16 + lr;
          out[(size_t)tok * Dc + (size_t)z * 128 + cl] = acc[mi][ni][g];
        }
      }
    }
}

// ---------------------------------------------------------------------------
// Scan: one block per (b,e); 128 threads = state dim. Ballot-build the time-
// ordered match list, then chunk-stage a/bu/c/sk through LDS so the serial
// chain is LDS-read + fma (not global-latency). Emits y as bf16 hi/lo.
// ---------------------------------------------------------------------------
__global__ __launch_bounds__(128) void k_scan(
    const int* __restrict__ routes, const float* __restrict__ acts,
    u16* __restrict__ yH, u16* __restrict__ yL) {
  const int b = blockIdx.x, e = blockIdx.y;
  __shared__ int list[Tc];
  __shared__ int n_sh;
  __shared__ float As[16][128], Bs[16][128], Cs[16][128], Ss[16][128];
  const int tid = threadIdx.x;
  if (tid < 64) {
    int base = 0;
    for (int it = 0; it < Tc / 64; it++) {
      const int t = it * 64 + tid;
      const bool m = (routes[b * Tc + t] == e);
      const unsigned long long mask = __ballot(m);
      const int pre = __popcll(mask & ((1ull << tid) - 1ull));
      if (m) list[base + pre] = t;
      base += __popcll(mask);
    }
    if (tid == 0) n_sh = base;
  }
  __syncthreads();
  const int n = n_sh;
  const int s = tid;
  float h = 0.f;
  for (int c0 = 0; c0 < n; c0 += 16) {
#pragma unroll
    for (int i = 0; i < 16; i++) {
      const size_t tok = (size_t)(b * Tc + list[min(c0 + i, n - 1)]) * K4S;
      As[i][s] = acts[tok + s];
      Bs[i][s] = acts[tok + 128 + s];
      Cs[i][s] = acts[tok + 256 + s];
      Ss[i][s] = acts[tok + 384 + s];
    }
    __syncthreads();
    const int m = min(16, n - c0);
    for (int i = 0; i < m; i++) {
      h = fmaf(As[i][s], h, Bs[i][s]);
      const float yv = fmaf(Cs[i][s], h, Ss[i][s]);
      const size_t tok = (size_t)(b * Tc + list[c0 + i]) * Sc + s;
      u16 yh, yl; split2(yv, yh, yl);
      yH[tok] = yh; yL[tok] = yl;
    }
    __syncthreads();
  }
}

// ---------------------------------------------------------------------------
extern "C" void kernel_launch(void* const* d_in, const int* in_sizes, int n_in,
                              void* d_out, int out_size, void* d_ws, size_t ws_size,
                              hipStream_t stream) {
  const float* x         = (const float*)d_in[0];
  const int*   tok_ids   = (const int*)d_in[1];
  const float* W_in      = (const float*)d_in[2];
  const float* W_sel_in  = (const float*)d_in[3];
  const float* W_sel_out = (const float*)d_in[4];
  const float* W_out     = (const float*)d_in[5];
  const float* d_param   = (const float*)d_in[6];
  float* out = (float*)d_out;

  char* p = (char*)d_ws;
  auto carve = [&](size_t bytes) -> char* {
    char* r = p;
    p += (bytes + 255) / 256 * 256;
    return r;
  };
  int* routes   = (int*)carve((size_t)NTOK * 4);
  int* counts   = (int*)carve(Ec * 4);
  int* offs     = (int*)carve(Ec * 4);
  int* cursors  = (int*)carve(Ec * 4);
  int* tok_list = (int*)carve((size_t)NTOK * 4);
  u16* tInH = (u16*)carve((size_t)Ec * Sc * Dc * 2);
  u16* tInL = (u16*)carve((size_t)Ec * Sc * Dc * 2);
  u16* tSiH = (u16*)carve((size_t)Ec * Hc * Dc * 2);
  u16* tSiL = (u16*)carve((size_t)Ec * Hc * Dc * 2);
  u16* tSoH = (u16*)carve((size_t)Ec * K4S * Hc * 2);
  u16* tSoL = (u16*)carve((size_t)Ec * K4S * Hc * 2);
  u16* tOH  = (u16*)carve((size_t)Ec * Dc * Sc * 2);
  u16* tOL  = (u16*)carve((size_t)Ec * Dc * Sc * 2);
  float* u    = (float*)carve((size_t)NTOK * Sc * 4);     // dead after k_mm2
  u16* selhH  = (u16*)carve((size_t)NTOK * Hc * 2);
  u16* selhL  = (u16*)carve((size_t)NTOK * Hc * 2);
  float* acts = (float*)carve((size_t)NTOK * K4S * 4);
  u16* yH = (u16*)u;                                       // y aliases dead u (8MB)
  u16* yL = yH + (size_t)NTOK * Sc;

  k_zero<<<1, 64, 0, stream>>>(counts);
  k_route<<<NTOK / 256, 256, 0, stream>>>(tok_ids, routes, counts);
  k_offsets<<<1, 64, 0, stream>>>(counts, offs, cursors);
  k_scatter<<<NTOK / 256, 256, 0, stream>>>(routes, cursors, tok_list);
  k_tr_split<<<5120, 256, 0, stream>>>(W_in, W_sel_in, W_sel_out, W_out,
                                       tInH, tInL, tSiH, tSiL, tSoH, tSoL, tOH, tOL);
  // grid.x=24 tiles of 128 rows covers up to 3072 tokens/expert (mean 2048).
  k_mm1<<<dim3(24, Ec, 3), 256, 0, stream>>>(x, tInH, tInL, tSiH, tSiL,
                                             tok_list, offs, counts, u, selhH, selhL);
  k_mm2<<<dim3(24, Ec, 4), 256, 0, stream>>>(selhH, selhL, tSoH, tSoL, u, d_param,
                                             tok_list, offs, counts, acts);
  k_scan<<<dim3(Bc, Ec), 128, 0, stream>>>(routes, acts, yH, yL);
  k_mm3<<<dim3(24, Ec, 8), 256, 0, stream>>>(yH, yL, tOH, tOL,
                                             tok_list, offs, counts, out);
}